// Round 1
// baseline (334.899 us; speedup 1.0000x reference)
//
#include <hip/hip_runtime.h>
#include <stdint.h>

// HydraAttention on MI355X (gfx950), R6.
// GEMM1/GEMM2 rebuilt as 256x256-tile, BK=32, 4-deep circular-buffer
// counted-vmcnt phase schedule (T2 swizzle + T3/T4 counted pipeline + T5
// setprio). 8 waves (2Mx4N), 512 thr, 128 KiB LDS, 1 block/CU.
// Pipeline: tile t+3 staged (global_load_lds) while computing tile t;
// gate = s_waitcnt vmcnt(8) once per K-tile (never 0 in steady state).
// Identity unchanged: out = invq[r] * (q @ (Wout*kv_b)^T) + b.

typedef short  short8   __attribute__((ext_vector_type(8)));
typedef float  floatx16 __attribute__((ext_vector_type(16)));

#define NT 32   // K=1024 / BK=32 k-tiles

__device__ __forceinline__ void async16(const void* g, void* l) {
  __builtin_amdgcn_global_load_lds((const __attribute__((address_space(1))) void*)g,
                                   (__attribute__((address_space(3))) void*)l, 16, 0, 0);
}

__device__ __forceinline__ uint16_t f2bf(float f) {  // RNE fp32->bf16
  union { float f; uint32_t u; } x; x.f = f;
  uint32_t u = x.u;
  return (uint16_t)((u + 0x7fffu + ((u >> 16) & 1u)) >> 16);
}
__device__ __forceinline__ float bf2f(uint16_t h) {
  union { uint32_t u; float f; } x; x.u = ((uint32_t)h) << 16; return x.f;
}
__device__ __forceinline__ uint32_t pack2(float a, float b) {
  return (uint32_t)f2bf(a) | ((uint32_t)f2bf(b) << 16);
}
__device__ __forceinline__ void upk8(uint4 u, float* f) {
  f[0]=bf2f((uint16_t)u.x); f[1]=bf2f((uint16_t)(u.x>>16));
  f[2]=bf2f((uint16_t)u.y); f[3]=bf2f((uint16_t)(u.y>>16));
  f[4]=bf2f((uint16_t)u.z); f[5]=bf2f((uint16_t)(u.z>>16));
  f[6]=bf2f((uint16_t)u.w); f[7]=bf2f((uint16_t)(u.w>>16));
}

// ---------------- fused fp32->bf16 convert of 3 buffers ----------------
__global__ __launch_bounds__(256) void cvt3(
    const float* __restrict__ a, uint16_t* __restrict__ ao, int na,
    const float* __restrict__ b, uint16_t* __restrict__ bo, int nb,
    const float* __restrict__ c, uint16_t* __restrict__ co, int nc) {
  int i = blockIdx.x * 256 + threadIdx.x;
  const float* in; uint16_t* out; int j = i;
  if (j < na) { in = a; out = ao; }
  else {
    j -= na;
    if (j < nb) { in = b; out = bo; }
    else { j -= nb; if (j >= nc) return; in = c; out = co; }
  }
  const float4* p = (const float4*)in;
  float4 u = p[(size_t)j * 2], v = p[(size_t)j * 2 + 1];
  uint4 o;
  o.x = pack2(u.x, u.y); o.y = pack2(u.z, u.w);
  o.z = pack2(v.x, v.y); o.w = pack2(v.z, v.w);
  ((uint4*)out)[j] = o;
}

// ---- one pipeline phase: 6 ds_read_b128 | stage issues | barrier |
//      lgkmcnt(0) | prio1 | 8x mfma 32x32x16 | prio0 | gate | barrier ----
// Reads rows: A = wm*128 + {0,32,64,96} + l31 ; B = wn*64 + {0,32} + l31.
// Swizzle: linear slot = kc ^ ((row>>1)&3) = kc ^ ((l31>>1)&3) = kc ^ rsw.
#define MFMA_PHASE(Ac, Bc, kcv, STAGE, GATE) { \
    const int slot_ = (((kcv) ^ rsw) * 8); \
    const uint16_t* Ap_ = (Ac) + slot_; \
    const uint16_t* Bp_ = (Bc) + slot_; \
    short8 a0_ = *(const short8*)&Ap_[(wm * 128 +  0 + l31) * 32]; \
    short8 a1_ = *(const short8*)&Ap_[(wm * 128 + 32 + l31) * 32]; \
    short8 a2_ = *(const short8*)&Ap_[(wm * 128 + 64 + l31) * 32]; \
    short8 a3_ = *(const short8*)&Ap_[(wm * 128 + 96 + l31) * 32]; \
    short8 b0_ = *(const short8*)&Bp_[(wn * 64 +  0 + l31) * 32]; \
    short8 b1_ = *(const short8*)&Bp_[(wn * 64 + 32 + l31) * 32]; \
    STAGE; \
    __builtin_amdgcn_sched_barrier(0); \
    __builtin_amdgcn_s_barrier(); \
    asm volatile("s_waitcnt lgkmcnt(0)" ::: "memory"); \
    __builtin_amdgcn_s_setprio(1); \
    acc[0][0] = __builtin_amdgcn_mfma_f32_32x32x16_bf16(a0_, b0_, acc[0][0], 0, 0, 0); \
    acc[0][1] = __builtin_amdgcn_mfma_f32_32x32x16_bf16(a0_, b1_, acc[0][1], 0, 0, 0); \
    acc[1][0] = __builtin_amdgcn_mfma_f32_32x32x16_bf16(a1_, b0_, acc[1][0], 0, 0, 0); \
    acc[1][1] = __builtin_amdgcn_mfma_f32_32x32x16_bf16(a1_, b1_, acc[1][1], 0, 0, 0); \
    acc[2][0] = __builtin_amdgcn_mfma_f32_32x32x16_bf16(a2_, b0_, acc[2][0], 0, 0, 0); \
    acc[2][1] = __builtin_amdgcn_mfma_f32_32x32x16_bf16(a2_, b1_, acc[2][1], 0, 0, 0); \
    acc[3][0] = __builtin_amdgcn_mfma_f32_32x32x16_bf16(a3_, b0_, acc[3][0], 0, 0, 0); \
    acc[3][1] = __builtin_amdgcn_mfma_f32_32x32x16_bf16(a3_, b1_, acc[3][1], 0, 0, 0); \
    __builtin_amdgcn_s_setprio(0); \
    GATE; \
    __builtin_amdgcn_sched_barrier(0); \
    __builtin_amdgcn_s_barrier(); \
  }

// ---------------- GEMM1: qkv[16384,3072] = bf16( x @ Wqkv^T + bias ) ------
__global__ __launch_bounds__(512, 2) void gemm1(
    const uint16_t* __restrict__ A, const uint16_t* __restrict__ Bw,
    const float* __restrict__ bias, uint16_t* __restrict__ Cb)
{
  __shared__ __align__(16) uint16_t As[4][8192];   // 4 bufs x 256r x 32c
  __shared__ __align__(16) uint16_t Bs[4][8192];
  const int tid = threadIdx.x;
  const int wave = tid >> 6, lane = tid & 63;
  const int l31 = lane & 31, khalf = lane >> 5;
  const int rsw = (l31 >> 1) & 3;
  const int wm = wave & 1, wn = wave >> 1;          // 2M x 4N waves
  const int id = blockIdx.x;
  const int xcd = id & 7, w = id >> 3;              // 768 blocks, 96/XCD
  const int tileM = ((w / 12) * 8 + xcd) * 256;     // 64 M-tiles
  const int tileN = (w % 12) * 256;                 // 12 N-tiles

  // staging: 512 thr, 4 thr/row, 128 rows/issue; source slot pre-swizzled
  const int srow = tid >> 2;
  const int sk   = (tid & 3) ^ ((tid >> 3) & 3);
  const uint16_t* gA = A  + (size_t)(tileM + srow) * 1024 + sk * 8;
  const uint16_t* gB = Bw + (size_t)(tileN + srow) * 1024 + sk * 8;

  floatx16 acc[4][2];
#pragma unroll
  for (int mi = 0; mi < 4; mi++)
#pragma unroll
    for (int ni = 0; ni < 2; ni++)
#pragma unroll
      for (int r = 0; r < 16; r++) acc[mi][ni][r] = 0.f;

  // prologue: stage tiles 0..2; gate tile0 landed (8 = tiles 1,2 in flight)
#pragma unroll
  for (int t = 0; t < 3; ++t) {
    const size_t ko = (size_t)t * 32;
    async16(gA + ko,                      (char*)As[t] + wave * 1024);
    async16(gA + ko + (size_t)128 * 1024, (char*)As[t] + 8192 + wave * 1024);
    async16(gB + ko,                      (char*)Bs[t] + wave * 1024);
    async16(gB + ko + (size_t)128 * 1024, (char*)Bs[t] + 8192 + wave * 1024);
  }
  asm volatile("s_waitcnt vmcnt(8)" ::: "memory");
  __builtin_amdgcn_s_barrier();

#define STG_A1(tt) if ((tt) < NT) { const int c3_ = (tt) & 3; const size_t ko_ = (size_t)(tt) * 32; \
    async16(gA + ko_,                      (char*)As[c3_] + wave * 1024); \
    async16(gA + ko_ + (size_t)128 * 1024, (char*)As[c3_] + 8192 + wave * 1024); }
#define STG_B1(tt) if ((tt) < NT) { const int c3_ = (tt) & 3; const size_t ko_ = (size_t)(tt) * 32; \
    async16(gB + ko_,                      (char*)Bs[c3_] + wave * 1024); \
    async16(gB + ko_ + (size_t)128 * 1024, (char*)Bs[c3_] + 8192 + wave * 1024); }
#define GATE_ if (t + 3 < NT) { asm volatile("s_waitcnt vmcnt(8)" ::: "memory"); } \
    else if (t + 2 < NT) { asm volatile("s_waitcnt vmcnt(4)" ::: "memory"); } \
    else if (t + 1 < NT) { asm volatile("s_waitcnt vmcnt(0)" ::: "memory"); }

#pragma unroll 1
  for (int t = 0; t < NT; ++t) {
    const uint16_t* Ac = As[t & 3];
    const uint16_t* Bc = Bs[t & 3];
    MFMA_PHASE(Ac, Bc, khalf,     STG_A1(t + 3), )
    MFMA_PHASE(Ac, Bc, khalf + 2, STG_B1(t + 3), GATE_)
  }
#undef STG_A1
#undef STG_B1
#undef GATE_

  // C/D layout 32x32: col = lane&31, row = (reg&3) + 8*(reg>>2) + 4*(lane>>5)
#pragma unroll
  for (int mi = 0; mi < 4; mi++) {
    const int rbase = tileM + wm * 128 + mi * 32 + 4 * khalf;
#pragma unroll
    for (int ni = 0; ni < 2; ni++) {
      const int col = tileN + wn * 64 + ni * 32 + l31;
      const float bv = bias[col];
#pragma unroll
      for (int reg = 0; reg < 16; reg++) {
        const int row = rbase + (reg & 3) + 8 * (reg >> 2);
        Cb[(size_t)row * 3072 + col] = f2bf(acc[mi][ni][reg] + bv);
      }
    }
  }
}

// ---------------- GEMM2: out[16384,1024] = invq[r]*(q @ W'^T) + b ---------
__global__ __launch_bounds__(512, 2) void gemm2(
    const uint16_t* __restrict__ qkv, const float* __restrict__ invq,
    const uint16_t* __restrict__ Wp, const float* __restrict__ bias,
    float* __restrict__ Cf)
{
  __shared__ __align__(16) uint16_t As[4][8192];
  __shared__ __align__(16) uint16_t Bs[4][8192];
  const int tid = threadIdx.x;
  const int wave = tid >> 6, lane = tid & 63;
  const int l31 = lane & 31, khalf = lane >> 5;
  const int rsw = (l31 >> 1) & 3;
  const int wm = wave & 1, wn = wave >> 1;
  const int id = blockIdx.x;                        // 256 blocks = 1/CU
  const int tileM = (id >> 2) * 256;
  const int tileN = (id & 3) * 256;
  const int batch = tileM >> 12;

  const int srow = tid >> 2;
  const int sk   = (tid & 3) ^ ((tid >> 3) & 3);
  const uint16_t* gA = qkv + (size_t)(tileM + srow) * 3072 + sk * 8;  // q slice
  const uint16_t* gB = Wp + ((size_t)batch << 20) + (size_t)(tileN + srow) * 1024 + sk * 8;

  floatx16 acc[4][2];
#pragma unroll
  for (int mi = 0; mi < 4; mi++)
#pragma unroll
    for (int ni = 0; ni < 2; ni++)
#pragma unroll
      for (int r = 0; r < 16; r++) acc[mi][ni][r] = 0.f;

#pragma unroll
  for (int t = 0; t < 3; ++t) {
    const size_t ko = (size_t)t * 32;
    async16(gA + ko,                      (char*)As[t] + wave * 1024);
    async16(gA + ko + (size_t)128 * 3072, (char*)As[t] + 8192 + wave * 1024);
    async16(gB + ko,                      (char*)Bs[t] + wave * 1024);
    async16(gB + ko + (size_t)128 * 1024, (char*)Bs[t] + 8192 + wave * 1024);
  }
  asm volatile("s_waitcnt vmcnt(8)" ::: "memory");
  __builtin_amdgcn_s_barrier();

#define STG_A2(tt) if ((tt) < NT) { const int c3_ = (tt) & 3; const size_t ko_ = (size_t)(tt) * 32; \
    async16(gA + ko_,                      (char*)As[c3_] + wave * 1024); \
    async16(gA + ko_ + (size_t)128 * 3072, (char*)As[c3_] + 8192 + wave * 1024); }
#define STG_B2(tt) if ((tt) < NT) { const int c3_ = (tt) & 3; const size_t ko_ = (size_t)(tt) * 32; \
    async16(gB + ko_,                      (char*)Bs[c3_] + wave * 1024); \
    async16(gB + ko_ + (size_t)128 * 1024, (char*)Bs[c3_] + 8192 + wave * 1024); }
#define GATE_ if (t + 3 < NT) { asm volatile("s_waitcnt vmcnt(8)" ::: "memory"); } \
    else if (t + 2 < NT) { asm volatile("s_waitcnt vmcnt(4)" ::: "memory"); } \
    else if (t + 1 < NT) { asm volatile("s_waitcnt vmcnt(0)" ::: "memory"); }

#pragma unroll 1
  for (int t = 0; t < NT; ++t) {
    const uint16_t* Ac = As[t & 3];
    const uint16_t* Bc = Bs[t & 3];
    MFMA_PHASE(Ac, Bc, khalf,     STG_A2(t + 3), )
    MFMA_PHASE(Ac, Bc, khalf + 2, STG_B2(t + 3), GATE_)
  }
#undef STG_A2
#undef STG_B2
#undef GATE_

#pragma unroll
  for (int mi = 0; mi < 4; mi++) {
    const int rbase = tileM + wm * 128 + mi * 32 + 4 * khalf;
#pragma unroll
    for (int ni = 0; ni < 2; ni++) {
      const int col = tileN + wn * 64 + ni * 32 + l31;
      const float bv = bias[col];
#pragma unroll
      for (int reg = 0; reg < 16; reg++) {
        const int row = rbase + (reg & 3) + 8 * (reg >> 2);
        Cf[(size_t)row * 1024 + col] = fmaf(invq[row], acc[mi][ni][reg], bv);
      }
    }
  }
}

// ---------------- W'[b][n][k] = bf16( Wout[n][k] * kv[b][k] ) ----------------
__global__ __launch_bounds__(256) void scale_w(
    const uint16_t* __restrict__ wo, const float* __restrict__ kv,
    uint16_t* __restrict__ wp)
{
  int i = blockIdx.x * 256 + threadIdx.x;   // 4M elems / 8 = 512K threads
  int e = i << 3;
  int b = e >> 20;
  int k = e & 1023;
  uint4 w = *(const uint4*)(wo + (e & 0xFFFFF));
  float4 k0v = *(const float4*)(kv + (b << 10) + k);
  float4 k1v = *(const float4*)(kv + (b << 10) + k + 4);
  float wf[8]; upk8(w, wf);
  uint4 o;
  o.x = pack2(wf[0] * k0v.x, wf[1] * k0v.y);
  o.y = pack2(wf[2] * k0v.z, wf[3] * k0v.w);
  o.z = pack2(wf[4] * k1v.x, wf[5] * k1v.y);
  o.w = pack2(wf[6] * k1v.z, wf[7] * k1v.w);
  *(uint4*)(wp + e) = o;
}

// ---------------- mask layout detection ----------------
__global__ __launch_bounds__(256) void detect_mask(const unsigned char* __restrict__ m,
                                                   int* __restrict__ flag) {
  int i = blockIdx.x * blockDim.x + threadIdx.x;
  int v = ((i & 3) != 0) ? (int)m[i] : 0;
  unsigned long long b = __ballot(v != 0);
  if ((threadIdx.x & 63) == 0 && b) atomicOr(flag, 1);
}

// ---------------- per-row norms + kv reduction (512 blocks) ----------------
__global__ __launch_bounds__(256) void rownorm_kv(
    const uint16_t* __restrict__ qkv, const void* __restrict__ maskbuf,
    const int* __restrict__ flag, float* __restrict__ invq, float* __restrict__ kv)
{
  __shared__ float kvloc[1024];
  const int tid = threadIdx.x;
  for (int i = tid; i < 1024; i += 256) kvloc[i] = 0.f;
  __syncthreads();
  const int wave = tid >> 6, lane = tid & 63;
  const int b = blockIdx.x >> 7;
  const int chunk = blockIdx.x & 127;
  const int isU8 = *flag;
  const unsigned char* m8 = (const unsigned char*)maskbuf;
  const int* m32 = (const int*)maskbuf;

  float kvacc[16];
#pragma unroll
  for (int i = 0; i < 16; i++) kvacc[i] = 0.f;

  const int r0 = b * 4096 + chunk * 32 + wave * 8;
#pragma unroll 2
  for (int j = 0; j < 8; j++) {
    int r = r0 + j;
    const uint16_t* rp = qkv + (size_t)r * 3072;
    uint4 q0 = *(const uint4*)(rp + lane * 16);
    uint4 q1 = *(const uint4*)(rp + lane * 16 + 8);
    uint4 k0 = *(const uint4*)(rp + 1024 + lane * 16);
    uint4 k1 = *(const uint4*)(rp + 1024 + lane * 16 + 8);
    uint4 v0 = *(const uint4*)(rp + 2048 + lane * 16);
    uint4 v1 = *(const uint4*)(rp + 2048 + lane * 16 + 8);
    float qf[16], kf[16], vf[16];
    upk8(q0, qf); upk8(q1, qf + 8);
    upk8(k0, kf); upk8(k1, kf + 8);
    upk8(v0, vf); upk8(v1, vf + 8);
    float sq = 0.f, sk = 0.f;
#pragma unroll
    for (int i = 0; i < 16; i++) { sq = fmaf(qf[i], qf[i], sq); sk = fmaf(kf[i], kf[i], sk); }
    for (int off = 32; off; off >>= 1) { sq += __shfl_xor(sq, off); sk += __shfl_xor(sk, off); }
    float rq = rsqrtf(sq), rk = rsqrtf(sk);
    if (lane == 0) invq[r] = rq;
    int masked = isU8 ? (int)m8[r] : m32[r];
    if (!masked) {
#pragma unroll
      for (int i = 0; i < 16; i++) kvacc[i] = fmaf(kf[i] * rk, vf[i], kvacc[i]);
    }
  }
#pragma unroll
  for (int i = 0; i < 16; i++) atomicAdd(&kvloc[lane * 16 + i], kvacc[i]);
  __syncthreads();
  for (int i = tid; i < 1024; i += 256) atomicAdd(&kv[b * 1024 + i], kvloc[i]);
}

extern "C" void kernel_launch(void* const* d_in, const int* in_sizes, int n_in,
                              void* d_out, int out_size, void* d_ws, size_t ws_size,
                              hipStream_t stream) {
  const float* x     = (const float*)d_in[0];
  const void*  mask  = d_in[1];
  const float* W_qkv = (const float*)d_in[2];
  const float* b_qkv = (const float*)d_in[3];
  const float* W_out = (const float*)d_in[4];
  const float* b_out = (const float*)d_in[5];
  float* out = (float*)d_out;

  const int BT = 4 * 4096;  // 16384 rows
  const int D  = 1024;

  char* ws = (char*)d_ws;
  size_t off = 0;
  auto alloc = [&](size_t bytes) { size_t r = off; off += (bytes + 255) & ~(size_t)255; return r; };
  size_t o_xb   = alloc((size_t)BT * D * 2);        // x bf16
  size_t o_qkvb = alloc((size_t)BT * 3 * D * 2);    // qkv bf16
  size_t o_wq   = alloc((size_t)3 * D * D * 2);     // W_qkv bf16
  size_t o_wo   = alloc((size_t)D * D * 2);         // W_out bf16
  size_t o_wp   = alloc((size_t)4 * D * D * 2);     // W' = Wout*kv_b, per batch
  size_t o_kv   = alloc((size_t)4 * D * 4 + 256);   // kv (fp32) + flag
  size_t o_invq = alloc((size_t)BT * 4);            // 1/||q|| per row

  uint16_t* xb   = (uint16_t*)(ws + o_xb);
  uint16_t* qkvb = (uint16_t*)(ws + o_qkvb);
  uint16_t* wq   = (uint16_t*)(ws + o_wq);
  uint16_t* wo   = (uint16_t*)(ws + o_wo);
  uint16_t* wp   = (uint16_t*)(ws + o_wp);
  float*    kv   = (float*)(ws + o_kv);
  int*      flag = (int*)(ws + o_kv + (size_t)4 * D * 4);
  float*    invq = (float*)(ws + o_invq);

  hipMemsetAsync(ws + o_kv, 0, (size_t)4 * D * 4 + 256, stream);
  {
    int na = BT * D / 8, nb = 3 * D * D / 8, nc = D * D / 8;
    int tot = na + nb + nc;
    cvt3<<<dim3((tot + 255) / 256), 256, 0, stream>>>(x, xb, na, W_qkv, wq, nb, W_out, wo, nc);
  }
  detect_mask<<<dim3(64), 256, 0, stream>>>((const unsigned char*)mask, flag);
  gemm1<<<dim3(768), 512, 0, stream>>>(xb, wq, b_qkv, qkvb);
  rownorm_kv<<<dim3(512), 256, 0, stream>>>(qkvb, mask, flag, invq, kv);
  scale_w<<<dim3(4 * D * D / 8 / 256), 256, 0, stream>>>(wo, kv, wp);
  gemm2<<<dim3(256), 512, 0, stream>>>(qkvb, invq, wp, b_out, out);
}